// Round 1
// baseline (2032.647 us; speedup 1.0000x reference)
//
#include <hip/hip_runtime.h>
#include <math.h>

#define BB 8
#define SS 512
#define DD 512
#define HH 8
#define HD 64
#define FF 2048
#define LL 6
#define VV 32000
#define BS (BB*SS)   // 4096

typedef _Float16 f16;
typedef _Float16 f16x8 __attribute__((ext_vector_type(8)));
typedef _Float16 f16x4 __attribute__((ext_vector_type(4)));
typedef float    f32x4 __attribute__((ext_vector_type(4)));
typedef unsigned int u32x4 __attribute__((ext_vector_type(4)));

// ---------------------------------------------------------------------------
// f32 -> f16 convert (vectorized)
__global__ void cvt_f32_f16(const float* __restrict__ s, f16* __restrict__ d, int n4) {
    int i = blockIdx.x * 256 + threadIdx.x;
    if (i >= n4) return;
    f32x4 v = *(const f32x4*)(s + (size_t)i * 4);
    f16x4 o;
    o[0] = (f16)v[0]; o[1] = (f16)v[1]; o[2] = (f16)v[2]; o[3] = (f16)v[3];
    *(f16x4*)(d + (size_t)i * 4) = o;
}

// ---------------------------------------------------------------------------
// h = emb[x] + pos ; also f16 copy
__global__ void embed_k(const int* __restrict__ x, const float* __restrict__ emb,
                        const float* __restrict__ pos, float* __restrict__ h,
                        f16* __restrict__ h16) {
    int i = blockIdx.x * 256 + threadIdx.x;       // < BS*DD = 2M
    int d  = i & (DD - 1);
    int bs = i >> 9;
    int s  = bs & (SS - 1);
    float v = emb[(size_t)x[bs] * DD + d] + pos[(size_t)s * DD + d];
    h[i]   = v;
    h16[i] = (f16)v;
}

// ---------------------------------------------------------------------------
// Generic C[M,N] = A[M,K] @ B[N,K]^T + bias ; OUT_MODE 0: f32, 1: f16, 2: f16+relu
// M%128==0, N%128==0, K%32==0 (all shapes here satisfy this)
template<int OUT_MODE>
__global__ __launch_bounds__(256, 2)
void gemm_bt(const f16* __restrict__ A, const f16* __restrict__ B,
             const float* __restrict__ bias, float* __restrict__ Cf,
             f16* __restrict__ Ch, int M, int N, int K) {
    __shared__ f16 sA[128 * 40];
    __shared__ f16 sB[128 * 40];
    const int t = threadIdx.x;
    const int w = t >> 6, l = t & 63;
    const int m0 = blockIdx.y * 128, n0 = blockIdx.x * 128;
    const int wm = (w & 1) * 64, wn = (w >> 1) * 64;
    const int rl = l & 15, koff = 8 * (l >> 4);
    f32x4 acc[4][4] = {};
    const int r0 = t >> 2, c0 = (t & 3) * 8;   // slots t and t+256
    const int r1 = 64 + r0;
    const f16* Arow0 = A + (size_t)(m0 + r0) * K + c0;
    const f16* Arow1 = A + (size_t)(m0 + r1) * K + c0;
    const f16* Brow0 = B + (size_t)(n0 + r0) * K + c0;
    const f16* Brow1 = B + (size_t)(n0 + r1) * K + c0;
    for (int k0 = 0; k0 < K; k0 += 32) {
        *(u32x4*)&sA[r0 * 40 + c0] = *(const u32x4*)(Arow0 + k0);
        *(u32x4*)&sA[r1 * 40 + c0] = *(const u32x4*)(Arow1 + k0);
        *(u32x4*)&sB[r0 * 40 + c0] = *(const u32x4*)(Brow0 + k0);
        *(u32x4*)&sB[r1 * 40 + c0] = *(const u32x4*)(Brow1 + k0);
        __syncthreads();
        f16x8 af[4], bfr[4];
        #pragma unroll
        for (int mt = 0; mt < 4; ++mt)
            af[mt] = *(const f16x8*)&sA[(wm + mt * 16 + rl) * 40 + koff];
        #pragma unroll
        for (int nt = 0; nt < 4; ++nt)
            bfr[nt] = *(const f16x8*)&sB[(wn + nt * 16 + rl) * 40 + koff];
        #pragma unroll
        for (int mt = 0; mt < 4; ++mt)
            #pragma unroll
            for (int nt = 0; nt < 4; ++nt)
                acc[mt][nt] = __builtin_amdgcn_mfma_f32_16x16x32_f16(af[mt], bfr[nt], acc[mt][nt], 0, 0, 0);
        __syncthreads();
    }
    const int rb = 4 * (l >> 4);
    #pragma unroll
    for (int nt = 0; nt < 4; ++nt) {
        const int n = n0 + wn + nt * 16 + rl;
        const float bv = bias[n];
        #pragma unroll
        for (int mt = 0; mt < 4; ++mt) {
            #pragma unroll
            for (int ri = 0; ri < 4; ++ri) {
                const int m = m0 + wm + mt * 16 + rb + ri;
                float v = acc[mt][nt][ri] + bv;
                if (OUT_MODE == 2) v = fmaxf(v, 0.0f);
                if (OUT_MODE == 0) Cf[(size_t)m * N + n] = v;
                else               Ch[(size_t)m * N + n] = (f16)v;
            }
        }
    }
}

// ---------------------------------------------------------------------------
// transpose V slice of qkv into vT[b,h,hd,s]
__global__ void vtrans(const f16* __restrict__ qkv, f16* __restrict__ vT) {
    __shared__ f16 tile[64][65];
    const int t = threadIdx.x;
    const int st = blockIdx.x, bh = blockIdx.y;
    const int b = bh >> 3, h = bh & 7;
    const int s0 = st * 64;
    #pragma unroll
    for (int i = 0; i < 16; ++i) {
        int lin = i * 256 + t;
        int sl = lin >> 6, dl = lin & 63;
        tile[sl][dl] = qkv[(size_t)(b * SS + s0 + sl) * (3 * DD) + 2 * DD + h * HD + dl];
    }
    __syncthreads();
    #pragma unroll
    for (int i = 0; i < 16; ++i) {
        int lin = i * 256 + t;
        int dl = lin >> 6, sl = lin & 63;
        vT[((size_t)bh * HD + dl) * SS + s0 + sl] = tile[sl][dl];
    }
}

// ---------------------------------------------------------------------------
// fused attention: one block per (16 q-rows, head). 256 threads = 4 waves.
__global__ __launch_bounds__(256, 2)
void attn_kernel(const f16* __restrict__ qkv, const f16* __restrict__ vT,
                 f16* __restrict__ O) {
    __shared__ float sS[16][520];
    __shared__ f16   sP[16][520];
    const int t = threadIdx.x;
    const int w = t >> 6, l = t & 63;
    const int qt = blockIdx.x, bh = blockIdx.y;
    const int b = bh >> 3, h = bh & 7;
    const int q0 = qt * 16;
    const int rl = l & 15, koff = 8 * (l >> 4);
    // Q fragments (A operand): row = q0+rl, k = d
    f16x8 qa0, qa1;
    {
        const f16* qrow = qkv + (size_t)(b * SS + q0 + rl) * (3 * DD) + h * HD + koff;
        qa0 = *(const f16x8*)(qrow);
        qa1 = *(const f16x8*)(qrow + 32);
    }
    // scores: wave w covers key-cols [w*128, w*128+128)
    const f16* kbase = qkv + (size_t)(b * SS) * (3 * DD) + DD + h * HD;
    #pragma unroll
    for (int nt = 0; nt < 8; ++nt) {
        const int ncol = w * 128 + nt * 16;
        const f16* krow = kbase + (size_t)(ncol + rl) * (3 * DD) + koff;
        f16x8 kb0 = *(const f16x8*)(krow);
        f16x8 kb1 = *(const f16x8*)(krow + 32);
        f32x4 acc = {0.f, 0.f, 0.f, 0.f};
        acc = __builtin_amdgcn_mfma_f32_16x16x32_f16(qa0, kb0, acc, 0, 0, 0);
        acc = __builtin_amdgcn_mfma_f32_16x16x32_f16(qa1, kb1, acc, 0, 0, 0);
        const int cc = ncol + rl;
        const int rr = 4 * (l >> 4);
        #pragma unroll
        for (int ri = 0; ri < 4; ++ri) sS[rr + ri][cc] = acc[ri] * 0.125f;
    }
    __syncthreads();
    // softmax: 16 threads per row
    {
        const int r = t >> 4, cl = t & 15;
        float vals[32];
        float mx = -1e30f;
        #pragma unroll
        for (int j = 0; j < 32; ++j) { float v = sS[r][cl + 16 * j]; vals[j] = v; mx = fmaxf(mx, v); }
        #pragma unroll
        for (int o = 1; o < 16; o <<= 1) mx = fmaxf(mx, __shfl_xor(mx, o));
        float sum = 0.f;
        #pragma unroll
        for (int j = 0; j < 32; ++j) { float e = __expf(vals[j] - mx); vals[j] = e; sum += e; }
        #pragma unroll
        for (int o = 1; o < 16; o <<= 1) sum += __shfl_xor(sum, o);
        const float inv = 1.0f / sum;
        #pragma unroll
        for (int j = 0; j < 32; ++j) sP[r][cl + 16 * j] = (f16)(vals[j] * inv);
    }
    __syncthreads();
    // PV: wave w covers out-cols [w*16, w*16+16)
    f32x4 oacc = {0.f, 0.f, 0.f, 0.f};
    {
        const f16* vbase = vT + ((size_t)bh * HD + w * 16 + rl) * SS + koff;
        #pragma unroll
        for (int kk = 0; kk < SS; kk += 32) {
            f16x8 pa = *(const f16x8*)&sP[rl][kk + koff];
            f16x8 vb = *(const f16x8*)(vbase + kk);
            oacc = __builtin_amdgcn_mfma_f32_16x16x32_f16(pa, vb, oacc, 0, 0, 0);
        }
    }
    {
        const int col = h * HD + w * 16 + rl;
        const int rbase = q0 + 4 * (l >> 4);
        #pragma unroll
        for (int ri = 0; ri < 4; ++ri)
            O[(size_t)(b * SS + rbase + ri) * DD + col] = (f16)oacc[ri];
    }
}

// ---------------------------------------------------------------------------
// h = LayerNorm(hin + proj) ; writes f32 and f16
__global__ void add_ln(const float* __restrict__ hin, const float* __restrict__ proj,
                       const float* __restrict__ g, const float* __restrict__ bta,
                       float* __restrict__ hout, f16* __restrict__ h16) {
    const int r = blockIdx.x, t = threadIdx.x;
    const size_t base = (size_t)r * DD;
    float v0 = hin[base + t]       + proj[base + t];
    float v1 = hin[base + t + 256] + proj[base + t + 256];
    float s = v0 + v1, ss = v0 * v0 + v1 * v1;
    #pragma unroll
    for (int o = 1; o < 64; o <<= 1) { s += __shfl_xor(s, o); ss += __shfl_xor(ss, o); }
    __shared__ float rs[4], rss[4];
    if ((t & 63) == 0) { rs[t >> 6] = s; rss[t >> 6] = ss; }
    __syncthreads();
    s  = rs[0] + rs[1] + rs[2] + rs[3];
    ss = rss[0] + rss[1] + rss[2] + rss[3];
    const float mu  = s * (1.0f / DD);
    const float var = ss * (1.0f / DD) - mu * mu;
    const float rstd = rsqrtf(var + 1e-5f);
    float o0 = g[t]       * (v0 - mu) * rstd + bta[t];
    float o1 = g[t + 256] * (v1 - mu) * rstd + bta[t + 256];
    hout[base + t] = o0;       hout[base + t + 256] = o1;
    h16 [base + t] = (f16)o0;  h16 [base + t + 256] = (f16)o1;
}

// ---------------------------------------------------------------------------
// triad pass 1: per-row sum and sum-of-squares
__global__ void rowstats(const float* __restrict__ h, float* __restrict__ rowsum,
                         float* __restrict__ sqpart) {
    const int r = blockIdx.x, t = threadIdx.x;
    const size_t base = (size_t)r * DD;
    float v0 = h[base + t], v1 = h[base + t + 256];
    float s = v0 + v1, ss = v0 * v0 + v1 * v1;
    #pragma unroll
    for (int o = 1; o < 64; o <<= 1) { s += __shfl_xor(s, o); ss += __shfl_xor(ss, o); }
    __shared__ float rs[4], rss[4];
    if ((t & 63) == 0) { rs[t >> 6] = s; rss[t >> 6] = ss; }
    __syncthreads();
    if (t == 0) {
        rowsum[r] = rs[0] + rs[1] + rs[2] + rs[3];
        sqpart[r] = rss[0] + rss[1] + rss[2] + rss[3];
    }
}

// triad pass 2: norm, g, exact quantile(0.75) via bitonic sort, addvec
__global__ void sortsel(const float* __restrict__ rowsum, const float* __restrict__ sqpart,
                        float* __restrict__ addvec, float damp) {
    __shared__ float a[BS];
    __shared__ float red[16];
    const int t = threadIdx.x;   // 1024 threads
    float ss = sqpart[t] + sqpart[t + 1024] + sqpart[t + 2048] + sqpart[t + 3072];
    #pragma unroll
    for (int o = 1; o < 64; o <<= 1) ss += __shfl_xor(ss, o);
    if ((t & 63) == 0) red[t >> 6] = ss;
    __syncthreads();
    if (t == 0) {
        float tot = 0.f;
        for (int i = 0; i < 16; ++i) tot += red[i];
        red[0] = sqrtf(tot);
    }
    __syncthreads();
    const float norm = red[0];
    const float inv = 1.0f / ((float)DD * (norm + 1e-8f));
    #pragma unroll
    for (int m = 0; m < 4; ++m) { int i = t + m * 1024; a[i] = fabsf(rowsum[i] * inv); }
    __syncthreads();
    for (int k = 2; k <= BS; k <<= 1) {
        for (int j = k >> 1; j > 0; j >>= 1) {
            #pragma unroll
            for (int m = 0; m < 4; ++m) {
                int i = t + m * 1024;
                int ixj = i ^ j;
                if (ixj > i) {
                    float xv = a[i], yv = a[ixj];
                    bool up = ((i & k) == 0);
                    if ((xv > yv) == up) { a[i] = yv; a[ixj] = xv; }
                }
            }
            __syncthreads();
        }
    }
    const float thr = a[3071] + 0.25f * (a[3072] - a[3071]);
    if (t < DD) {
        float gj = rowsum[t] * inv;
        addvec[t] = (fabsf(gj) > thr) ? damp * gj : 0.0f;
    }
}

// triad pass 3: h += addvec broadcast ; refresh f16 copy
__global__ void addrow(float* __restrict__ h, f16* __restrict__ h16,
                       const float* __restrict__ addvec) {
    int i = blockIdx.x * 256 + threadIdx.x;
    float v = h[i] + addvec[i & (DD - 1)];
    h[i] = v;
    h16[i] = (f16)v;
}

// ---------------------------------------------------------------------------
extern "C" void kernel_launch(void* const* d_in, const int* in_sizes, int n_in,
                              void* d_out, int out_size, void* d_ws, size_t ws_size,
                              hipStream_t stream) {
    const int*   x    = (const int*)d_in[0];
    const float* emb  = (const float*)d_in[1];
    const float* pos  = (const float*)d_in[2];
    const float* ipw  = (const float*)d_in[3];
    const float* ipb  = (const float*)d_in[4];
    const float* ow   = (const float*)d_in[5];
    const float* ob   = (const float*)d_in[6];
    const float* l1g  = (const float*)d_in[7];
    const float* l1b  = (const float*)d_in[8];
    const float* l2g  = (const float*)d_in[9];
    const float* l2b  = (const float*)d_in[10];
    const float* f1w  = (const float*)d_in[11];
    const float* f1b  = (const float*)d_in[12];
    const float* f2w  = (const float*)d_in[13];
    const float* f2b  = (const float*)d_in[14];
    const float* wout = (const float*)d_in[15];
    const float* bout = (const float*)d_in[16];
    float* out = (float*)d_out;

    char* ws = (char*)d_ws;
    size_t off = 0;
    auto alloc = [&](size_t bytes) -> char* {
        char* p = ws + off;
        off += (bytes + 511) & ~(size_t)511;
        return p;
    };
    float* h      = (float*)alloc((size_t)BS * DD * 4);
    f16*   h16    = (f16*)  alloc((size_t)BS * DD * 2);
    f16*   qkv    = (f16*)  alloc((size_t)BS * 3 * DD * 2);
    f16*   vT     = (f16*)  alloc((size_t)BB * HH * HD * SS * 2);
    f16*   attO   = (f16*)  alloc((size_t)BS * DD * 2);
    f16*   ffb    = (f16*)  alloc((size_t)BS * FF * 2);
    float* tmp    = (float*)alloc((size_t)BS * DD * 4);
    f16*   w_ip   = (f16*)  alloc((size_t)LL * 3 * DD * DD * 2);
    f16*   w_o    = (f16*)  alloc((size_t)LL * DD * DD * 2);
    f16*   w_f1   = (f16*)  alloc((size_t)LL * FF * DD * 2);
    f16*   w_f2   = (f16*)  alloc((size_t)LL * DD * FF * 2);
    f16*   w_lg   = (f16*)  alloc((size_t)VV * DD * 2);
    float* rowsum = (float*)alloc((size_t)BS * 4);
    float* sqpart = (float*)alloc((size_t)BS * 4);
    float* addvec = (float*)alloc((size_t)DD * 4);

    auto cvt = [&](const float* s, f16* d, size_t n) {
        int n4 = (int)(n / 4);
        cvt_f32_f16<<<dim3((n4 + 255) / 256), dim3(256), 0, stream>>>(s, d, n4);
    };
    cvt(ipw,  w_ip, (size_t)LL * 3 * DD * DD);
    cvt(ow,   w_o,  (size_t)LL * DD * DD);
    cvt(f1w,  w_f1, (size_t)LL * FF * DD);
    cvt(f2w,  w_f2, (size_t)LL * DD * FF);
    cvt(wout, w_lg, (size_t)VV * DD);

    embed_k<<<dim3(BS * DD / 256), dim3(256), 0, stream>>>(x, emb, pos, h, h16);

    for (int l = 0; l < LL; ++l) {
        // QKV projection -> qkv (f16)
        gemm_bt<1><<<dim3(3 * DD / 128, BS / 128), dim3(256), 0, stream>>>(
            h16, w_ip + (size_t)l * 3 * DD * DD, ipb + (size_t)l * 3 * DD,
            nullptr, qkv, BS, 3 * DD, DD);
        // V transpose
        vtrans<<<dim3(SS / 64, BB * HH), dim3(256), 0, stream>>>(qkv, vT);
        // fused attention -> attO
        attn_kernel<<<dim3(SS / 16, BB * HH), dim3(256), 0, stream>>>(qkv, vT, attO);
        // output projection -> tmp (f32)
        gemm_bt<0><<<dim3(DD / 128, BS / 128), dim3(256), 0, stream>>>(
            attO, w_o + (size_t)l * DD * DD, ob + (size_t)l * DD,
            tmp, nullptr, BS, DD, DD);
        // h = LN(h + tmp)
        add_ln<<<dim3(BS), dim3(256), 0, stream>>>(
            h, tmp, l1g + (size_t)l * DD, l1b + (size_t)l * DD, h, h16);
        // FFN1 + relu -> ffb (f16)
        gemm_bt<2><<<dim3(FF / 128, BS / 128), dim3(256), 0, stream>>>(
            h16, w_f1 + (size_t)l * FF * DD, f1b + (size_t)l * FF,
            nullptr, ffb, BS, FF, DD);
        // FFN2 -> tmp (f32)
        gemm_bt<0><<<dim3(DD / 128, BS / 128), dim3(256), 0, stream>>>(
            ffb, w_f2 + (size_t)l * DD * FF, f2b + (size_t)l * DD,
            tmp, nullptr, BS, DD, FF);
        // h = LN(h + tmp)
        add_ln<<<dim3(BS), dim3(256), 0, stream>>>(
            h, tmp, l2g + (size_t)l * DD, l2b + (size_t)l * DD, h, h16);
    }

    const float damp = (float)pow(0.99, 1.0 / 6.0);
    for (int c = 0; c < LL; ++c) {
        rowstats<<<dim3(BS), dim3(256), 0, stream>>>(h, rowsum, sqpart);
        sortsel<<<dim3(1), dim3(1024), 0, stream>>>(rowsum, sqpart, addvec, damp);
        addrow<<<dim3(BS * DD / 256), dim3(256), 0, stream>>>(h, h16, addvec);
    }

    // logits = h @ Wout^T + bout  -> d_out (f32)
    gemm_bt<0><<<dim3(VV / 128, BS / 128), dim3(256), 0, stream>>>(
        h16, w_lg, bout, out, nullptr, BS, VV, DD);
}